// Round 1
// baseline (132.807 us; speedup 1.0000x reference)
//
#include <hip/hip_runtime.h>

// Problem constants (fixed by reference)
constexpr int Bn = 4, Cn = 64, Hn = 192, Wn = 640;
constexpr int TH = 8, TW = 64;            // output tile per block
constexpr int SH = TH + 4, SW = TW + 4;   // 12 x 68 tile+halo
constexpr int NS = SH * SW;               // 816
constexpr int NT = 512;                   // threads per block (1 px/thread)

__global__ __launch_bounds__(NT, 4) void guide_triplet_kernel(
    const float* __restrict__ pred,
    const int*   __restrict__ target,
    float* __restrict__ out)
{
    __shared__ float slice[2][NS];
    __shared__ float sumsq[NS];
    __shared__ float invn[NS];
    __shared__ int   lbl[NS];

    const int x0 = blockIdx.x * TW;
    const int y0 = blockIdx.y * TH;
    const int b  = blockIdx.z;

    const int tid = threadIdx.x;
    const int tx  = tid & (TW - 1);   // 0..63
    const int ty  = tid >> 6;         // 0..7

    // Precompute staging addresses (2 slice elements per thread, 2nd partial)
    const int e0 = tid;
    const int e1 = tid + NT;
    const bool has1 = (e1 < NS);           // tid < 304
    const int r0 = e0 / SW, c0 = e0 % SW;
    const int r1 = e1 / SW, c1 = e1 % SW;
    const int gy0 = y0 + r0 - 2, gx0 = x0 + c0 - 2;
    const int gy1 = y0 + r1 - 2, gx1 = x0 + c1 - 2;
    const bool ok0 = (gy0 >= 0) && (gy0 < Hn) && (gx0 >= 0) && (gx0 < Wn);
    const bool ok1 = has1 && (gy1 >= 0) && (gy1 < Hn) && (gx1 >= 0) && (gx1 < Wn);
    const int off0 = gy0 * Wn + gx0;
    const int off1 = gy1 * Wn + gx1;

    // Stage labels (pad = -1) and zero the sumsq accumulators (owner-thread only)
    {
        const int* tb = target + b * Hn * Wn;
        lbl[e0]   = ok0 ? tb[off0] : -1;
        sumsq[e0] = 0.0f;
        if (has1) {
            lbl[e1]   = ok1 ? tb[off1] : -1;
            sumsq[e1] = 0.0f;
        }
    }

    float acc[25];
    #pragma unroll
    for (int k = 0; k < 25; ++k) acc[k] = 0.0f;

    const float* predb = pred + (size_t)b * Cn * Hn * Wn;
    const int cbase = (ty + 2) * SW + (tx + 2);

    // Channel loop: stage slice (double-buffered, 1 barrier/channel),
    // accumulate raw dot products + per-pixel sum of squares.
    for (int c = 0; c < Cn; ++c) {
        const float* pc = predb + c * (Hn * Wn);
        float* sb = slice[c & 1];
        float v0 = ok0 ? pc[off0] : 0.0f;
        sb[e0] = v0;
        sumsq[e0] += v0 * v0;
        if (has1) {
            float v1 = ok1 ? pc[off1] : 0.0f;
            sb[e1] = v1;
            sumsq[e1] += v1 * v1;
        }
        __syncthreads();   // slice[c&1] ready; also fences re-write 2 iters later
        float f = sb[cbase];
        #pragma unroll
        for (int di = 0; di < 5; ++di) {
            #pragma unroll
            for (int dj = 0; dj < 5; ++dj) {
                acc[di * 5 + dj] = fmaf(f, sb[(ty + di) * SW + (tx + dj)],
                                        acc[di * 5 + dj]);
            }
        }
        // no second barrier: double buffer + next iteration's barrier protect reuse
    }

    // Inverse norms for tile+halo (owner-thread write, then block-visible)
    invn[e0] = 1.0f / fmaxf(sqrtf(sumsq[e0]), 1e-12f);
    if (has1) invn[e1] = 1.0f / fmaxf(sqrtf(sumsq[e1]), 1e-12f);
    __syncthreads();

    const float ic = invn[cbase];
    const int   lc = lbl[cbase];

    float pos_num = 0.0f, neg_num = 0.0f, pos_sum = 0.0f, neg_sum = 0.0f;
    #pragma unroll
    for (int di = 0; di < 5; ++di) {
        #pragma unroll
        for (int dj = 0; dj < 5; ++dj) {
            const int e = (ty + di) * SW + (tx + dj);
            const float sim = acc[di * 5 + dj] * ic * invn[e];
            const float aff = sqrtf(fmaxf(1e-9f, 2.0f - 2.0f * sim));
            const float mf  = (lbl[e] == lc) ? 1.0f : 0.0f;
            pos_num += mf;
            neg_num += 1.0f - mf;
            pos_sum = fmaf(mf, aff, pos_sum);
            neg_sum = fmaf(1.0f - mf, aff, neg_sum);
        }
    }
    const bool boundary = (pos_num >= 4.0f) && (neg_num >= 4.0f);
    const float tri = fmaxf(0.0f,
        pos_sum / pos_num - neg_sum / fmaxf(neg_num, 1e-12f) + 0.3f);
    out[((size_t)b * Hn + (y0 + ty)) * Wn + (x0 + tx)] = boundary ? tri : 0.0f;
}

extern "C" void kernel_launch(void* const* d_in, const int* in_sizes, int n_in,
                              void* d_out, int out_size, void* d_ws, size_t ws_size,
                              hipStream_t stream) {
    const float* pred   = (const float*)d_in[0];
    const int*   target = (const int*)d_in[1];
    float*       out    = (float*)d_out;
    dim3 grid(Wn / TW, Hn / TH, Bn);   // 10 x 24 x 4 = 960 blocks
    guide_triplet_kernel<<<grid, NT, 0, stream>>>(pred, target, out);
}